// Round 12
// baseline (249.664 us; speedup 1.0000x reference)
//
#include <hip/hip_runtime.h>
#include <hip/hip_fp16.h>
#include <math.h>

// LinearCaps2d, BATCH=256, N = B_TYPES*H*W = 2048, C=10, POSE=16, 3 routing iters.
// R24 = R23 at grid 1024: the clean "hoist + no-spill + 4 blocks/CU" test that
// R21 attempted but spilled. R23 dropped VGPR to 100 (28 regs headroom) by
// deleting the weight-LDS machinery -- geometry change is now register-safe.
//   (1) grid 1024 = 256 n-groups (8 n) x 4 b-groups; 4 blocks/CU, 16 waves/CU
//       (2x R23's TLP). VGPR 100 -> 4 waves/SIMD = 400 regs <= 512 ok;
//   (2) ZERO barriers: R23 audit showed each wave stages/reads only its own 16
//       xs rows (staging, bx reads, transpose scratch all wave-private);
//   (3) weights direct global->reg, 1-n-ahead prefetch (R23-verified);
//       per-block weight slice halves to 80 KB (L1-friendlier);
//   (4) xs row stride 140 f16 (dword stride 70 === 6 mod 32, the verified
//       low-conflict residue class); LDS 17920 B;
//   (5) atomic payload doubles to ~43 MB WRITE (R16-verified clean at 1024).
// Discriminating prediction: TLP-bound -> pass ~33-40us; invariant -> ~50us.
// Spill tripwire: WRITE > 55 MB or VGPR > 115 -> revert to R20.
// ws: s0,s1,s2 [40960] f32.

typedef _Float16 f16;
typedef _Float16 f16x2 __attribute__((ext_vector_type(2)));
typedef _Float16 f16x4 __attribute__((ext_vector_type(4)));
typedef __fp16   h16x2 __attribute__((ext_vector_type(2)));
typedef float f32x4 __attribute__((ext_vector_type(4)));

__device__ __forceinline__ f16x2 pk(float a, float b) {
    h16x2 t = __builtin_amdgcn_cvt_pkrtz(a, b);
    return __builtin_bit_cast(f16x2, t);
}

#if __has_builtin(__builtin_amdgcn_fdot2)
__device__ __forceinline__ float FDOT2(f16x2 a, f16x2 b, float c) {
    return __builtin_amdgcn_fdot2(__builtin_bit_cast(h16x2, a),
                                  __builtin_bit_cast(h16x2, b), c, false);
}
#else
__device__ __forceinline__ float FDOT2(f16x2 a, f16x2 b, float c) {
    return c + (float)a[0] * (float)b[0] + (float)a[1] * (float)b[1];
}
#endif

// xs row stride in f16: 140 -> dword stride 70 === 6 (mod 32), verified class.
constexpr int XR = 140;

__device__ __forceinline__ float xorsum4(float v) {
    v += __shfl_xor(v, 16, 64);
    v += __shfl_xor(v, 32, 64);
    return v;
}

// packed f16x2 cross-quad reduction: one shfl pair for two c's (verified R11)
__device__ __forceinline__ f16x2 xorsum4h(f16x2 v) {
    union { f16x2 h; int i; } u;
    union { int i; f16x2 h; } w;
    u.h = v; w.i = __shfl_xor(u.i, 16, 64); v = v + w.h;
    u.h = v; w.i = __shfl_xor(u.i, 32, 64); v = v + w.h;
    return v;
}

__device__ __forceinline__ f16x4 cvt4(float4 w) {
    f16x2 a = pk(w.x, w.y);
    f16x2 b = pk(w.z, w.w);
    f16x4 r; r[0] = a[0]; r[1] = a[1]; r[2] = b[0]; r[3] = b[1];
    return r;
}

// grid: 1024 blocks = 256 n-groups (8 n) x 4 b-groups (64 b); 256 thr = 4 waves.
template<int PASS>
__global__ __launch_bounds__(256, 1)
void pass_k(const float* __restrict__ poses, const float* __restrict__ weight,
            const float* __restrict__ bias,
            const float* __restrict__ sp0, const float* __restrict__ sp1,
            float* __restrict__ s_dst)
{
    __shared__ f16 xs[64 * XR];   // 17920 B: 64 b x (8 n x 16 i) f16, padded rows

    const int tid  = threadIdx.x;
    const int blk  = blockIdx.x;
    const int ngrp = blk >> 2;          // 256 n-groups (8 n each)
    const int b0   = (blk & 3) * 64;    // 4 b-groups
    const int wave = tid >> 6;
    const int lane = tid & 63;
    const int q    = lane >> 4;
    const int lo   = lane & 15;
    const int wtb  = wave * 16;
    const int bg   = b0 + wtb;          // wave's global batch base

    // ---- direct weight fragments: lane's (n,c) chunk is contiguous 16 B at
    // wfrag + (n*10+c)*256; across the wave = coalesced 1 KB per (n,c).
    const float* wfrag = weight + (size_t)ngrp * 20480 + lo * 16 + q * 4;
    float4 wreg[10];
    auto load_wn = [&](int n) {
        #pragma unroll
        for (int c = 0; c < 10; ++c)
            wreg[c] = *(const float4*)(wfrag + (size_t)(n * 10 + c) * 256);
    };

    // hoist n=0 weight loads: HBM latency hides under xs staging + vsp preamble.
    load_wn(0);

    // ---- stage this block's poses: 64 b x 8 n x 16 i. Wave-private rows
    // (thread tid writes row tid>>2; wave w owns rows 16w..16w+15) -> NO barrier.
    const int b_loc = tid >> 2, part = tid & 3;
    {
        const float* xp = poses + (size_t)(b0 + b_loc) * 32768
                          + (size_t)ngrp * 128 + part * 32;
        float4 xr[8];
        #pragma unroll
        for (int j = 0; j < 8; ++j) xr[j] = ((const float4*)xp)[j];
        f16* lp = xs + b_loc * XR + part * 32;
        #pragma unroll
        for (int j = 0; j < 8; ++j) *(f16x4*)&lp[j * 4] = cvt4(xr[j]);
    }

    // ---- inline squash: vsp[c] = v[b=bg+lo][c][o=q*4..q*4+3], packed f16
    f16x2 vsp[10][2];
    if (PASS >= 1) {
        const int rowb = (bg + lo) * 10;
        #pragma unroll
        for (int c = 0; c < 10; ++c) {
            float4 bb = *(const float4*)(bias + c * 16 + q * 4);
            float4 sa = *(const float4*)(sp0 + (size_t)(rowb + c) * 16 + q * 4);
            float t0 = sa.x + bb.x, t1 = sa.y + bb.y, t2 = sa.z + bb.z, t3 = sa.w + bb.w;
            float n2 = xorsum4(t0*t0 + t1*t1 + t2*t2 + t3*t3);
            float sc = n2 / (1.f + n2) * rsqrtf(n2 + 1e-8f);
            float v0 = sc*t0, v1 = sc*t1, v2 = sc*t2, v3 = sc*t3;
            if (PASS == 2) {
                float4 sb = *(const float4*)(sp1 + (size_t)(rowb + c) * 16 + q * 4);
                float u0 = sb.x + bb.x, u1 = sb.y + bb.y, u2 = sb.z + bb.z, u3 = sb.w + bb.w;
                float m2 = xorsum4(u0*u0 + u1*u1 + u2*u2 + u3*u3);
                float sc2 = m2 / (1.f + m2) * rsqrtf(m2 + 1e-8f);
                v0 += sc2*u0; v1 += sc2*u1; v2 += sc2*u2; v3 += sc2*u3;
            }
            vsp[c][0] = pk(v0, v1);
            vsp[c][1] = pk(v2, v3);
        }
    }

    f32x4 acc[10];
    #pragma unroll
    for (int c = 0; c < 10; ++c) acc[c] = (f32x4){0.f, 0.f, 0.f, 0.f};

    // ---- main loop: 8 n, zero barriers, waves fully independent.
    #pragma unroll 2
    for (int n = 0; n < 8; ++n) {
        // consume wreg -> f16 fragments, then immediately issue n+1's batch.
        f16x4 awh[10];
        #pragma unroll
        for (int c = 0; c < 10; ++c) awh[c] = cvt4(wreg[c]);
        if (n < 7) load_wn(n + 1);

        f16x4 bx = *(const f16x4*)&xs[(wtb + lo) * XR + n * 16 + q * 4];
        f16x2 Vh[10][2];
        #pragma unroll
        for (int c = 0; c < 10; ++c) {
            f32x4 V = __builtin_amdgcn_mfma_f32_16x16x16f16(
                awh[c], bx, (f32x4){0.f, 0.f, 0.f, 0.f}, 0, 0, 0);
            Vh[c][0] = pk(V[0], V[1]);
            Vh[c][1] = pk(V[2], V[3]);
        }

        float cfv[10];
        if (PASS >= 1) {
            // logits: fdot2 on packed votes vs vsp; packed cross-quad reduce
            float lg[10];
            #pragma unroll
            for (int cp = 0; cp < 5; ++cp) {
                const int c0 = cp * 2, c1 = cp * 2 + 1;
                float p0 = FDOT2(Vh[c0][0], vsp[c0][0], 0.f);
                p0 = FDOT2(Vh[c0][1], vsp[c0][1], p0);
                float p1 = FDOT2(Vh[c1][0], vsp[c1][0], 0.f);
                p1 = FDOT2(Vh[c1][1], vsp[c1][1], p1);
                f16x2 pr = xorsum4h(pk(p0, p1));
                lg[c0] = (float)pr[0];
                lg[c1] = (float)pr[1];
            }
            float m = lg[0];
            #pragma unroll
            for (int c = 1; c < 10; ++c) m = fmaxf(m, lg[c]);
            float sum = 0.f;
            #pragma unroll
            for (int c = 0; c < 10; ++c) { lg[c] = __expf(lg[c] - m); sum += lg[c]; }
            const float inv = 1.f / sum;
            #pragma unroll
            for (int c = 0; c < 10; ++c) cfv[c] = lg[c] * inv;
        }

        // s-accumulate straight from packed votes
        #pragma unroll
        for (int c = 0; c < 10; ++c) {
            const float w = (PASS == 0) ? 1.f : cfv[c];
            acc[c][0] = fmaf(w, (float)Vh[c][0][0], acc[c][0]);
            acc[c][1] = fmaf(w, (float)Vh[c][0][1], acc[c][1]);
            acc[c][2] = fmaf(w, (float)Vh[c][1][0], acc[c][2]);
            acc[c][3] = fmaf(w, (float)Vh[c][1][1], acc[c][3]);
        }
    }

    // ---- wave-local LDS transpose (b<->o) + full-line atomic flush.
    // Reuse this wave's OWN xs rows (4480 B >= 1280 B needed); the wave's last
    // xs read (n=7) precedes these writes in program order (in-order DS ops);
    // other waves never touch this region. No barrier needed.
    float* trw = (float*)&xs[(size_t)wtb * XR];   // 16-B aligned (wave*4480 B)
    const float fs = (PASS == 0) ? 0.1f : 1.f;
    #pragma unroll
    for (int c = 0; c < 10; ++c) {
        // write own (b=lo, o=q*4..q*4+3); 16B-aligned b128
        *(float4*)&trw[lo * 20 + q * 4] = (float4){acc[c][0], acc[c][1], acc[c][2], acc[c][3]};
        // read (b=q*4+r, o=lo) -- wave-synchronous, in-order DS ops
        float r0 = trw[(q * 4 + 0) * 20 + lo];
        float r1 = trw[(q * 4 + 1) * 20 + lo];
        float r2 = trw[(q * 4 + 2) * 20 + lo];
        float r3 = trw[(q * 4 + 3) * 20 + lo];
        float* sp = s_dst + ((size_t)(bg + q * 4) * 10 + c) * 16 + lo;
        unsafeAtomicAdd(sp + 0 * 160, fs * r0);
        unsafeAtomicAdd(sp + 1 * 160, fs * r1);
        unsafeAtomicAdd(sp + 2 * 160, fs * r2);
        unsafeAtomicAdd(sp + 3 * 160, fs * r3);
    }
}

// final squash: 2560 rows, one (b,c) per thread (verified R3/R7).
__global__ __launch_bounds__(256)
void epi_k(const float* __restrict__ s2, const float* __restrict__ bias,
           float* __restrict__ out)
{
    const int t = blockIdx.x * 256 + threadIdx.x;
    if (t >= 2560) return;
    const int c = t % 10;
    const float* sp = s2 + (size_t)t * 16;
    const float* bp = bias + c * 16;
    float sv[16];
    float n2 = 0.f;
    #pragma unroll
    for (int o = 0; o < 16; ++o) { float v = sp[o] + bp[o]; sv[o] = v; n2 += v * v; }
    const float scale = n2 / (1.f + n2) * rsqrtf(n2 + 1e-8f);
    float a2 = 0.f;
    #pragma unroll
    for (int o = 0; o < 16; ++o) {
        float v = scale * sv[o];
        out[(size_t)t * 16 + o] = v;
        a2 += v * v;
    }
    out[40960 + t] = sqrtf(a2 + 1e-8f);
}

extern "C" void kernel_launch(void* const* d_in, const int* in_sizes, int n_in,
                              void* d_out, int out_size, void* d_ws, size_t ws_size,
                              hipStream_t stream)
{
    const float* poses  = (const float*)d_in[0];
    // d_in[1] (input_caps_activations) unused by the reference.
    const float* weight = (const float*)d_in[2];
    const float* bias   = (const float*)d_in[3];
    float* out = (float*)d_out;
    float* s0 = (float*)d_ws;
    float* s1 = s0 + 40960;
    float* s2 = s1 + 40960;

    (void)hipMemsetAsync(d_ws, 0, 3 * 40960 * sizeof(float), stream);

    pass_k<0><<<1024, 256, 0, stream>>>(poses, weight, bias, nullptr, nullptr, s0);
    pass_k<1><<<1024, 256, 0, stream>>>(poses, weight, bias, s0, nullptr, s1);
    pass_k<2><<<1024, 256, 0, stream>>>(poses, weight, bias, s0, s1, s2);
    epi_k<<<10, 256, 0, stream>>>(s2, bias, out);
}

// Round 14
// 202.167 us; speedup vs baseline: 1.2349x; 1.2349x over previous
//
#include <hip/hip_runtime.h>
#include <hip/hip_fp16.h>
#include <math.h>

// LinearCaps2d, BATCH=256, N = B_TYPES*H*W = 2048, C=10, POSE=16, 3 routing iters.
// R26 = R25 (f16 pre-conversion of weight+poses, amortized over 3 passes) with
// the OOB fixed: poses is 2,097,152 float4 (8,388,608 f32), NOT 4,194,304 --
// R25's prep_k read 2x past d_in[0] and crashed. Sizes corrected everywhere;
// bounds re-audited (wh max idx 5,242,879/5,242,880; xh max 8,388,607/8,388,608).
// Rationale (R24-corrected law): ~47us/pass @512 blocks is bytes-dominated --
// each pass re-fetches ~60 MB at ~1.9 TB/s. Converting f32->f16 ONCE halves
// unique bytes/pass 88 -> 44 MB; staging loads 16B -> 8B/lane; wreg pressure
// halves; fragment values bit-identical (same cvt_pkrtz rounding).
// ws need 27.75 MB: s0,s1,s2 (491 KB) + wh (10.5 MB) + xh (16.8 MB).
// Fallback if ws too small: R20-verbatim f32 path (201.5us proven).

typedef _Float16 f16;
typedef _Float16 f16x2 __attribute__((ext_vector_type(2)));
typedef _Float16 f16x4 __attribute__((ext_vector_type(4)));
typedef __fp16   h16x2 __attribute__((ext_vector_type(2)));
typedef float f32x4 __attribute__((ext_vector_type(4)));

__device__ __forceinline__ f16x2 pk(float a, float b) {
    h16x2 t = __builtin_amdgcn_cvt_pkrtz(a, b);
    return __builtin_bit_cast(f16x2, t);
}

#if __has_builtin(__builtin_amdgcn_fdot2)
__device__ __forceinline__ float FDOT2(f16x2 a, f16x2 b, float c) {
    return __builtin_amdgcn_fdot2(__builtin_bit_cast(h16x2, a),
                                  __builtin_bit_cast(h16x2, b), c, false);
}
#else
__device__ __forceinline__ float FDOT2(f16x2 a, f16x2 b, float c) {
    return c + (float)a[0] * (float)b[0] + (float)a[1] * (float)b[1];
}
#endif

constexpr int WS_ROW = 28;   // f16 row stride (16 i + 12 pad) -- R7's low-conflict value
constexpr int XS_ROW = 76;   // f16 row stride (4n x 16 i + pad)

__device__ __forceinline__ float xorsum4(float v) {
    v += __shfl_xor(v, 16, 64);
    v += __shfl_xor(v, 32, 64);
    return v;
}

// packed f16x2 cross-quad reduction: one shfl pair for two c's (verified R11)
__device__ __forceinline__ f16x2 xorsum4h(f16x2 v) {
    union { f16x2 h; int i; } u;
    union { int i; f16x2 h; } w;
    u.h = v; w.i = __shfl_xor(u.i, 16, 64); v = v + w.h;
    u.h = v; w.i = __shfl_xor(u.i, 32, 64); v = v + w.h;
    return v;
}

__device__ __forceinline__ f16x4 cvt4(float4 w) {
    f16x2 a = pk(w.x, w.y);
    f16x2 b = pk(w.z, w.w);
    f16x4 r; r[0] = a[0]; r[1] = a[1]; r[2] = b[0]; r[3] = b[1];
    return r;
}

// ---- one-time f32 -> f16 conversion. weight = 1,310,720 float4 (verified:
// 32*8*8*10*16*16 f32); poses = 2,097,152 float4 (256*2048*16 f32). Coalesced
// grid-stride.
__global__ __launch_bounds__(256)
void prep_k(const float* __restrict__ w, const float* __restrict__ x,
            f16* __restrict__ wh, f16* __restrict__ xh)
{
    const size_t W4 = 1310720, X4 = 2097152;
    for (size_t i = (size_t)blockIdx.x * 256 + threadIdx.x; i < W4 + X4;
         i += (size_t)gridDim.x * 256) {
        if (i < W4) {
            float4 v = ((const float4*)w)[i];
            ((f16x4*)wh)[i] = cvt4(v);
        } else {
            const size_t j = i - W4;
            float4 v = ((const float4*)x)[j];
            ((f16x4*)xh)[j] = cvt4(v);
        }
    }
}

// grid: 512 blocks = 128 n-groups (16 n) x 4 b-groups (64 b); 256 thr = 4 waves.
// HALF=1: poses/weight pointers are pre-converted f16 (8B staging loads).
// HALF=0: R20-verbatim f32 path (fallback).
template<int PASS, int HALF>
__global__ __launch_bounds__(256, 2)
void pass_k(const void* __restrict__ poses, const void* __restrict__ weight,
            const float* __restrict__ bias,
            const float* __restrict__ sp0, const float* __restrict__ sp1,
            float* __restrict__ s_dst)
{
    __shared__ f16 Ws[640 * WS_ROW];   // 35840 B (reused as transpose buffer at end)
    __shared__ f16 xs[64 * XS_ROW];    //  9728 B

    const int tid  = threadIdx.x;
    const int blk  = blockIdx.x;
    const int ngrp = blk >> 2;          // 128 n-groups (16 n each)
    const int b0   = (blk & 3) * 64;    // 4 b-groups
    const int wave = tid >> 6;
    const int lane = tid & 63;
    const int q    = lane >> 4;
    const int lo   = lane & 15;
    const int wtb  = wave * 16;
    const int bg   = b0 + wtb;          // wave's global batch base

    // ---- staging registers + loaders (issue-early hoist, R20-verified).
    float4 wreg[10];  float4 xreg[4];    // f32 path
    f16x4  wregh[10]; f16x4  xregh[4];   // f16 path (half the registers)
    const int b_loc = tid >> 2, part = tid & 3;

    auto load_w = [&](int l) {
        if constexpr (HALF) {
            const f16* wp = (const f16*)weight + (size_t)(ngrp * 4 + l) * 10240;
            #pragma unroll
            for (int k = 0; k < 10; ++k) wregh[k] = ((const f16x4*)wp)[tid + k * 256];
        } else {
            const float* wp = (const float*)weight + (size_t)(ngrp * 4 + l) * 10240;
            #pragma unroll
            for (int k = 0; k < 10; ++k) wreg[k] = ((const float4*)wp)[tid + k * 256];
        }
    };
    auto load_x = [&](int l) {
        if constexpr (HALF) {
            const f16* xp = (const f16*)poses + (size_t)(b0 + b_loc) * 32768
                            + (size_t)(ngrp * 16 + l * 4 + part) * 16;
            #pragma unroll
            for (int j = 0; j < 4; ++j) xregh[j] = ((const f16x4*)xp)[j];
        } else {
            const float* xp = (const float*)poses + (size_t)(b0 + b_loc) * 32768
                              + (size_t)(ngrp * 16 + l * 4 + part) * 16;
            #pragma unroll
            for (int j = 0; j < 4; ++j) xreg[j] = ((const float4*)xp)[j];
        }
    };
    auto store_iter = [&]() {
        #pragma unroll
        for (int k = 0; k < 10; ++k) {
            const int f = tid + k * 256;          // f16x4 index in [0,2560)
            *(f16x4*)&Ws[(f >> 2) * WS_ROW + (f & 3) * 4] =
                HALF ? wregh[k] : cvt4(wreg[k]);
        }
        f16* lp = xs + b_loc * XS_ROW + part * 16;
        #pragma unroll
        for (int j = 0; j < 4; ++j)
            *(f16x4*)&lp[j * 4] = HALF ? xregh[j] : cvt4(xreg[j]);
    };

    // hoist: issue tile-0 weight loads first; latency hides under vsp preamble.
    load_w(0);

    // ---- inline squash: vsp[c] = v[b=bg+lo][c][o=q*4..q*4+3], packed f16
    f16x2 vsp[10][2];
    if (PASS >= 1) {
        const int rowb = (bg + lo) * 10;
        #pragma unroll
        for (int c = 0; c < 10; ++c) {
            float4 bb = *(const float4*)(bias + c * 16 + q * 4);
            float4 sa = *(const float4*)(sp0 + (size_t)(rowb + c) * 16 + q * 4);
            float t0 = sa.x + bb.x, t1 = sa.y + bb.y, t2 = sa.z + bb.z, t3 = sa.w + bb.w;
            float n2 = xorsum4(t0*t0 + t1*t1 + t2*t2 + t3*t3);
            float sc = n2 / (1.f + n2) * rsqrtf(n2 + 1e-8f);
            float v0 = sc*t0, v1 = sc*t1, v2 = sc*t2, v3 = sc*t3;
            if (PASS == 2) {
                float4 sb = *(const float4*)(sp1 + (size_t)(rowb + c) * 16 + q * 4);
                float u0 = sb.x + bb.x, u1 = sb.y + bb.y, u2 = sb.z + bb.z, u3 = sb.w + bb.w;
                float m2 = xorsum4(u0*u0 + u1*u1 + u2*u2 + u3*u3);
                float sc2 = m2 / (1.f + m2) * rsqrtf(m2 + 1e-8f);
                v0 += sc2*u0; v1 += sc2*u1; v2 += sc2*u2; v3 += sc2*u3;
            }
            vsp[c][0] = pk(v0, v1);
            vsp[c][1] = pk(v2, v3);
        }
    }

    // pose loads for tile 0 issue after the preamble.
    load_x(0);

    f32x4 acc[10];
    #pragma unroll
    for (int c = 0; c < 10; ++c) acc[c] = (f32x4){0.f, 0.f, 0.f, 0.f};

    for (int l = 0; l < 4; ++l) {
        __syncthreads();
        store_iter();
        if (l + 1 < 4) { load_w(l + 1); load_x(l + 1); }
        __syncthreads();

        #pragma unroll
        for (int n = 0; n < 4; ++n) {
            // votes^T fragments V[c][r] = votes[b=bg+lo][c][o=q*4+r] (R7 layout),
            // packed to f16 immediately to keep register pressure low.
            f16x4 bx = *(const f16x4*)&xs[(wtb + lo) * XS_ROW + n * 16 + q * 4];
            f16x2 Vh[10][2];
            #pragma unroll
            for (int c = 0; c < 10; ++c) {
                f16x4 aw = *(const f16x4*)&Ws[((n * 10 + c) * 16 + lo) * WS_ROW + q * 4];
                f32x4 V = __builtin_amdgcn_mfma_f32_16x16x16f16(
                    aw, bx, (f32x4){0.f, 0.f, 0.f, 0.f}, 0, 0, 0);
                Vh[c][0] = pk(V[0], V[1]);
                Vh[c][1] = pk(V[2], V[3]);
            }

            float cfv[10];
            if (PASS >= 1) {
                // logits: fdot2 on packed votes vs vsp; packed cross-quad reduce
                float lg[10];
                #pragma unroll
                for (int cp = 0; cp < 5; ++cp) {
                    const int c0 = cp * 2, c1 = cp * 2 + 1;
                    float p0 = FDOT2(Vh[c0][0], vsp[c0][0], 0.f);
                    p0 = FDOT2(Vh[c0][1], vsp[c0][1], p0);
                    float p1 = FDOT2(Vh[c1][0], vsp[c1][0], 0.f);
                    p1 = FDOT2(Vh[c1][1], vsp[c1][1], p1);
                    f16x2 pr = xorsum4h(pk(p0, p1));
                    lg[c0] = (float)pr[0];
                    lg[c1] = (float)pr[1];
                }
                float m = lg[0];
                #pragma unroll
                for (int c = 1; c < 10; ++c) m = fmaxf(m, lg[c]);
                float sum = 0.f;
                #pragma unroll
                for (int c = 0; c < 10; ++c) { lg[c] = __expf(lg[c] - m); sum += lg[c]; }
                const float inv = 1.f / sum;
                #pragma unroll
                for (int c = 0; c < 10; ++c) cfv[c] = lg[c] * inv;
            }

            // s-accumulate straight from packed votes
            #pragma unroll
            for (int c = 0; c < 10; ++c) {
                const float w = (PASS == 0) ? 1.f : cfv[c];
                acc[c][0] = fmaf(w, (float)Vh[c][0][0], acc[c][0]);
                acc[c][1] = fmaf(w, (float)Vh[c][0][1], acc[c][1]);
                acc[c][2] = fmaf(w, (float)Vh[c][1][0], acc[c][2]);
                acc[c][3] = fmaf(w, (float)Vh[c][1][1], acc[c][3]);
            }
        }
    }

    // ---- wave-local LDS transpose (b<->o) + full-line atomic flush.
    __syncthreads();                        // all waves done reading Ws/xs as f16
    float* tr = (float*)Ws + wave * 320;    // 320 floats/wave, stride-20 rows
    const float fs = (PASS == 0) ? 0.1f : 1.f;
    #pragma unroll
    for (int c = 0; c < 10; ++c) {
        // write own (b=lo, o=q*4..q*4+3); 16B-aligned b128
        *(float4*)&tr[lo * 20 + q * 4] = (float4){acc[c][0], acc[c][1], acc[c][2], acc[c][3]};
        // read (b=q*4+r, o=lo) -- wave-synchronous, in-order DS ops
        float r0 = tr[(q * 4 + 0) * 20 + lo];
        float r1 = tr[(q * 4 + 1) * 20 + lo];
        float r2 = tr[(q * 4 + 2) * 20 + lo];
        float r3 = tr[(q * 4 + 3) * 20 + lo];
        float* sp = s_dst + ((size_t)(bg + q * 4) * 10 + c) * 16 + lo;
        unsafeAtomicAdd(sp + 0 * 160, fs * r0);
        unsafeAtomicAdd(sp + 1 * 160, fs * r1);
        unsafeAtomicAdd(sp + 2 * 160, fs * r2);
        unsafeAtomicAdd(sp + 3 * 160, fs * r3);
    }
}

// final squash: 2560 rows, one (b,c) per thread (verified R3/R7).
__global__ __launch_bounds__(256)
void epi_k(const float* __restrict__ s2, const float* __restrict__ bias,
           float* __restrict__ out)
{
    const int t = blockIdx.x * 256 + threadIdx.x;
    if (t >= 2560) return;
    const int c = t % 10;
    const float* sp = s2 + (size_t)t * 16;
    const float* bp = bias + c * 16;
    float sv[16];
    float n2 = 0.f;
    #pragma unroll
    for (int o = 0; o < 16; ++o) { float v = sp[o] + bp[o]; sv[o] = v; n2 += v * v; }
    const float scale = n2 / (1.f + n2) * rsqrtf(n2 + 1e-8f);
    float a2 = 0.f;
    #pragma unroll
    for (int o = 0; o < 16; ++o) {
        float v = scale * sv[o];
        out[(size_t)t * 16 + o] = v;
        a2 += v * v;
    }
    out[40960 + t] = sqrtf(a2 + 1e-8f);
}

extern "C" void kernel_launch(void* const* d_in, const int* in_sizes, int n_in,
                              void* d_out, int out_size, void* d_ws, size_t ws_size,
                              hipStream_t stream)
{
    const float* poses  = (const float*)d_in[0];
    // d_in[1] (input_caps_activations) unused by the reference.
    const float* weight = (const float*)d_in[2];
    const float* bias   = (const float*)d_in[3];
    float* out = (float*)d_out;
    float* s0 = (float*)d_ws;
    float* s1 = s0 + 40960;
    float* s2 = s1 + 40960;

    // f16 staging buffers after the s-buffers (offset 491520 B, 8B-aligned).
    // wh: 5,242,880 halves (10.5 MB); xh: 8,388,608 halves (16.8 MB).
    f16* wh = (f16*)((char*)d_ws + 491520);
    f16* xh = wh + 5242880;
    const size_t need = 491520 + (size_t)(5242880 + 8388608) * 2;   // 27.75 MB
    const bool half = ws_size >= need;

    (void)hipMemsetAsync(d_ws, 0, 3 * 40960 * sizeof(float), stream);

    if (half) {
        prep_k<<<2048, 256, 0, stream>>>(weight, poses, wh, xh);
        pass_k<0, 1><<<512, 256, 0, stream>>>(xh, wh, bias, nullptr, nullptr, s0);
        pass_k<1, 1><<<512, 256, 0, stream>>>(xh, wh, bias, s0, nullptr, s1);
        pass_k<2, 1><<<512, 256, 0, stream>>>(xh, wh, bias, s0, s1, s2);
    } else {
        pass_k<0, 0><<<512, 256, 0, stream>>>(poses, weight, bias, nullptr, nullptr, s0);
        pass_k<1, 0><<<512, 256, 0, stream>>>(poses, weight, bias, s0, nullptr, s1);
        pass_k<2, 0><<<512, 256, 0, stream>>>(poses, weight, bias, s0, s1, s2);
    }
    epi_k<<<10, 256, 0, stream>>>(s2, bias, out);
}